// Round 13
// baseline (564.571 us; speedup 1.0000x reference)
//
#include <hip/hip_runtime.h>
#include <hip/hip_bf16.h>

// ---------------------------------------------------------------------------
// Decoder block for B=4, T=2048, E=1024, H=16, HD=64, V=32000.
// bf16 MFMA compute; post-LN model -> activations/residuals stored bf16.
// R13: flash staging rebalanced across all 8 waves (1 K gl_lds + 1/16 V-pack
//      each); residual-add fused into O-proj/FFN4 GEMM epilogues; add_ln
//      single-input when rb==null. Flash pipeline/swizzles = R12 (conflict-
//      free, measured); GEMM core = R10.
// ---------------------------------------------------------------------------

typedef __attribute__((ext_vector_type(8))) short v8s;    // 8 bf16 (4 VGPR)
typedef __attribute__((ext_vector_type(4))) short v4s;    // 4 bf16 (b64)
typedef __attribute__((ext_vector_type(4))) float v4f;    // 16x16 accumulator
typedef __attribute__((ext_vector_type(16))) float v16f;  // 32x32 accumulator
typedef __attribute__((ext_vector_type(4))) unsigned int v4u;

#define MFMA16(a, b, c) __builtin_amdgcn_mfma_f32_16x16x32_bf16((a), (b), (c), 0, 0, 0)
#define MFMA32(a, b, c) __builtin_amdgcn_mfma_f32_32x32x16_bf16((a), (b), (c), 0, 0, 0)

typedef const __attribute__((address_space(1))) void* gas1_t;
typedef __attribute__((address_space(3))) void* las3_t;

__device__ __forceinline__ void gl_lds16(const void* g, void* l) {
  __builtin_amdgcn_global_load_lds((gas1_t)g, (las3_t)l, 16, 0, 0);
}

__device__ __forceinline__ unsigned short f2bf(float f) {
  __hip_bfloat16 h = __float2bfloat16(f);
  return *reinterpret_cast<unsigned short*>(&h);
}

__device__ __forceinline__ float bf2f(unsigned short u) {
  union { unsigned int i; float f; } v;
  v.i = (unsigned int)u << 16;
  return v.f;
}

__device__ __forceinline__ float fast_exp2(float x) {
  float r;
  asm("v_exp_f32 %0, %1" : "=v"(r) : "v"(x));
  return r;
}

__device__ __forceinline__ unsigned int cvt_pk_bf16(float lo, float hi) {
  unsigned int r;
  asm("v_cvt_pk_bf16_f32 %0, %1, %2" : "=v"(r) : "v"(lo), "v"(hi));
  return r;
}

__device__ __forceinline__ float max3f(float a, float b, float c) {
  float r;
  asm("v_max3_f32 %0, %1, %2, %3" : "=v"(r) : "v"(a), "v"(b), "v"(c));
  return r;
}

// log2(e)/sqrt(HD) folded into the Q projection
#define QSCALE 0.18033688011112042f

// ---------------------------------------------------------------------------
// Batched weight prep: 12 matrices, src[K][N] f32 -> dst[N][K] bf16.
// ---------------------------------------------------------------------------
struct TransDesc {
  const float* src[12];
  unsigned short* dst[12];
};

__global__ __launch_bounds__(256)
void transpose_all(TransDesc td) {
  const int bid = blockIdx.x;
  int m, tile, K, N;
  if (bid < 8192) { m = bid >> 10; tile = bid & 1023; K = 1024; N = 1024; }
  else {
    const int r = bid - 8192;
    m = 8 + (r >> 9); tile = r & 511;
    if (m & 1) { K = 512; N = 1024; } else { K = 1024; N = 512; }
  }
  const float* src = td.src[m];
  unsigned short* dst = td.dst[m];
  const int ntx = N >> 5;
  const int n0 = (tile % ntx) * 32, k0 = (tile / ntx) * 32;

  __shared__ float tile_s[32][33];
  const int tx = threadIdx.x & 31, ty = threadIdx.x >> 5;  // 32 x 8
#pragma unroll
  for (int i = 0; i < 32; i += 8)
    tile_s[ty + i][tx] = src[(size_t)(k0 + ty + i) * N + n0 + tx];
  __syncthreads();
#pragma unroll
  for (int i = 0; i < 32; i += 8)
    dst[(size_t)(n0 + ty + i) * K + k0 + tx] = f2bf(tile_s[tx][ty + i]);
}

// ---------------------------------------------------------------------------
// Embedding: act = bf16(tok_emb[x] + pos_emb)
// ---------------------------------------------------------------------------
__global__ __launch_bounds__(256)
void embed_k(const int* __restrict__ x, const float* __restrict__ tok,
             const float* __restrict__ pos, unsigned short* __restrict__ act) {
  const int t = blockIdx.x, tid = threadIdx.x;
  const int id = x[t], tp = t & 2047;
  float4 v = ((const float4*)(tok + (size_t)id * 1024))[tid];
  float4 p = ((const float4*)(pos + (size_t)tp * 1024))[tid];
  ushort4 u;
  u.x = f2bf(v.x + p.x); u.y = f2bf(v.y + p.y);
  u.z = f2bf(v.z + p.z); u.w = f2bf(v.w + p.w);
  ((ushort4*)(act + (size_t)t * 1024))[tid] = u;
}

// ---------------------------------------------------------------------------
// GEMM: C[M][N] = A[M][K](bf16) @ Bt[N][K]^T(bf16)  (+bias) (+relu) (+resid)
// flags: bit0 relu, bit1 bf16 out, bit2 QSCALE on col<1024, bit3 add resid.
// 128x128 tile, BK=64, 4 waves (2x2), 2x2 32x32x16 MFMA per wave.
// Swizzled LDS (pre-swizzled staging + (row&7)*8 fragment XOR, conflict-free).
// C/D layout (m74/m101): col=lane&31, row=(reg&3)+8*(reg>>2)+4*(lane>>5).
// ---------------------------------------------------------------------------
__global__ __launch_bounds__(256)
void gemm_bt(const unsigned short* __restrict__ A, const unsigned short* __restrict__ Bt,
             const float* __restrict__ bias, const unsigned short* __restrict__ resid,
             void* __restrict__ C, int M, int N, int K, int flags) {
  __shared__ __align__(16) unsigned short As[128 * 64];
  __shared__ __align__(16) unsigned short Bs[128 * 64];
  const int tid = threadIdx.x;
  const int w = tid >> 6, l = tid & 63;
  const int l31 = l & 31, l5 = l >> 5;
  const int wm = w & 1, wn = w >> 1;
  const int m0 = blockIdx.x * 128, n0 = blockIdx.y * 128;
  const int ra = l >> 3, ka = ((l & 7) ^ (l >> 3)) * 8;  // pre-swizzled staging
  const int fswz = (l31 & 7) * 8;                         // fragment-read XOR

  v16f acc[2][2];
#pragma unroll
  for (int bm = 0; bm < 2; ++bm)
#pragma unroll
    for (int bn = 0; bn < 2; ++bn)
#pragma unroll
      for (int r = 0; r < 16; ++r) acc[bm][bn][r] = 0.f;

  for (int k0 = 0; k0 < K; k0 += 64) {
#pragma unroll
    for (int i = 0; i < 4; ++i) {
      const int c = w + i * 4;
      gl_lds16(A  + (size_t)(m0 + c * 8 + ra) * K + k0 + ka, &As[c * 512]);
      gl_lds16(Bt + (size_t)(n0 + c * 8 + ra) * K + k0 + ka, &Bs[c * 512]);
    }
    __syncthreads();
#pragma unroll
    for (int kk = 0; kk < 4; ++kk) {
      const int co = (kk * 16 + l5 * 8) ^ fswz;
      const v8s a0 = *(const v8s*)&As[(wm * 64 + l31) * 64 + co];
      const v8s a1 = *(const v8s*)&As[(wm * 64 + 32 + l31) * 64 + co];
      const v8s b0 = *(const v8s*)&Bs[(wn * 64 + l31) * 64 + co];
      const v8s b1 = *(const v8s*)&Bs[(wn * 64 + 32 + l31) * 64 + co];
      acc[0][0] = MFMA32(a0, b0, acc[0][0]);
      acc[0][1] = MFMA32(a0, b1, acc[0][1]);
      acc[1][0] = MFMA32(a1, b0, acc[1][0]);
      acc[1][1] = MFMA32(a1, b1, acc[1][1]);
    }
    __syncthreads();
  }

  const bool relu = flags & 1, obf = flags & 2, qs = flags & 4, ra_ = flags & 8;
#pragma unroll
  for (int bn = 0; bn < 2; ++bn) {
    const int col = n0 + wn * 64 + bn * 32 + l31;
    const float bv = bias ? bias[col] : 0.f;
    const float sc = (qs && col < 1024) ? QSCALE : 1.f;
#pragma unroll
    for (int bm = 0; bm < 2; ++bm) {
      const int rowbase = m0 + wm * 64 + bm * 32 + 4 * l5;
#pragma unroll
      for (int r = 0; r < 16; ++r) {
        const int row = rowbase + (r & 3) + 8 * (r >> 2);
        float v = (acc[bm][bn][r] + bv) * sc;
        if (relu) v = fmaxf(v, 0.f);
        if (ra_) v += bf2f(resid[(size_t)row * N + col]);
        if (obf) ((unsigned short*)C)[(size_t)row * N + col] = f2bf(v);
        else     ((float*)C)[(size_t)row * N + col] = v;
      }
    }
  }
}

// ---------------------------------------------------------------------------
// Flash attention over fused QKV buffer [8192][3072] bf16 (Q cols h*64..,
// K cols 1024+h*64.., V cols 2048+h*64..). 512 threads = 8 waves, 128 q
// rows/block. Single-barrier double-buffered K/V; staging balanced across
// ALL 8 waves: each wave issues 1 K gl_lds chunk (c = w) AND packs 1/16 of
// the V tile (2x b64 global loads -> 4 u32 LDS writes, 2 lanes/bank = free).
// Issue-early / write-late V prefetch. Swapped QK^T, in-reg softmax;
// Kt swz (kv&7)*8, Vt swz (d&15)*4 (measured conflict-free R7-R12).
// CAUSAL: 16 q-tiles of 128, block handles pair (bx, 15-bx).
// ---------------------------------------------------------------------------
#define LDQ 3072
template <bool CAUSAL>
__global__ __launch_bounds__(512)
void flash_attn(const unsigned short* __restrict__ qkv, unsigned short* __restrict__ O) {
  __shared__ __align__(16) unsigned short Kt[2][64 * 64];   // [kv][d], swizzled
  __shared__ __align__(16) unsigned short Vt[2][64 * 64];   // [d][kv], swizzled
  const int tid = threadIdx.x;
  const int w = tid >> 6, l = tid & 63, lr = l & 15, lg = l >> 4;
  const int b = blockIdx.y >> 4, h = blockIdx.y & 15;
  const size_t baseq = ((size_t)b * 2048) * LDQ + h * 64;   // QKV slice base
  const size_t baseo = ((size_t)b * 2048) * 1024 + h * 64;  // O slice base
  const int kswz = (lr & 7) * 8;    // K fragment-read XOR (elems)
  const int vswz = lr * 4;          // V fragment-read XOR: sigma(d)=(d&15)*4

  // K staging: wave w stages chunk w (8 kv rows); pre-swizzled global source
  const int kra = l >> 3, kka = ((l & 7) ^ (l >> 3)) * 8;
  const unsigned short* Kbase = qkv + baseq + 1024 + (size_t)(w * 8 + kra) * LDQ + kka;
  // V staging: thread -> kv pair (2 rows), d block of 4 (512 threads cover 64x64)
  const int vp_ = tid & 31, vd0 = (tid >> 5) * 4;
  const unsigned short* Vbase = qkv + baseq + 2048 + (size_t)(2 * vp_) * LDQ + vd0;

  const int nq = CAUSAL ? 2 : 1;
  for (int qi = 0; qi < nq; ++qi) {
    const int qt = CAUSAL ? (qi ? 15 - (int)blockIdx.x : (int)blockIdx.x)
                          : (int)blockIdx.x;
    const int q0w = qt * 128 + w * 16;                      // this wave's q base

    const unsigned short* qp = qkv + baseq + (size_t)(q0w + lr) * LDQ + lg * 8;
    const v8s qf0 = *(const v8s*)qp;
    const v8s qf1 = *(const v8s*)(qp + 32);

    v4f acc[4];
    const v4f vzero = {0.f, 0.f, 0.f, 0.f};
#pragma unroll
    for (int n = 0; n < 4; ++n) acc[n] = vzero;
    float mrow = -INFINITY, lrow = 0.f;                     // state for q = lr

    const int kv_end = CAUSAL ? qt * 128 + 128 : 2048;

    // ---- prologue: stage tile 0 into buffer 0 (all waves: K chunk + V part)
    {
      gl_lds16(Kbase, &Kt[0][w * 512]);
      const v4s v0 = *(const v4s*)Vbase;
      const v4s v1 = *(const v4s*)(Vbase + LDQ);
#pragma unroll
      for (int j = 0; j < 4; ++j) {
        const unsigned int pk = (unsigned int)(unsigned short)v0[j] |
                                ((unsigned int)(unsigned short)v1[j] << 16);
        *(unsigned int*)&Vt[0][(vd0 + j) * 64 + ((2 * vp_) ^ (((vd0 + j) & 15) * 4))] = pk;
      }
    }
    __syncthreads();

    int cur = 0;
    for (int kv0 = 0; kv0 < kv_end; kv0 += 64) {
      const bool have = (kv0 + 64) < kv_end;
      // ---- issue next-tile loads early (K async->LDS + V global->reg, all waves)
      v4s nv0, nv1;
      if (have) {
        const int nxt = kv0 + 64;
        gl_lds16(Kbase + (size_t)nxt * LDQ, &Kt[cur ^ 1][w * 512]);
        const unsigned short* va = Vbase + (size_t)nxt * LDQ;
        nv0 = *(const v4s*)va;
        nv1 = *(const v4s*)(va + LDQ);
      }

      // ---- S^T = mfma(K, Q): s[n][r] = S[kv = kv0+n*16+lg*4+r][q = q0w+lr]
      v4f s[4];
#pragma unroll
      for (int n = 0; n < 4; ++n) s[n] = vzero;
      __builtin_amdgcn_s_setprio(1);
#pragma unroll
      for (int kk = 0; kk < 2; ++kk) {
#pragma unroll
        for (int n = 0; n < 4; ++n) {
          const v8s kf = *(const v8s*)&Kt[cur][(n * 16 + lr) * 64 + ((kk * 32 + lg * 8) ^ kswz)];
          s[n] = MFMA16(kf, kk ? qf1 : qf0, s[n]);
        }
      }
      __builtin_amdgcn_s_setprio(0);

      if (CAUSAL && (kv0 + 63 > q0w)) {
        const int qg = q0w + lr;
#pragma unroll
        for (int n = 0; n < 4; ++n) {
          const int kvb = kv0 + n * 16 + lg * 4;
#pragma unroll
          for (int r = 0; r < 4; ++r)
            if (kvb + r > qg) s[n][r] = -INFINITY;
        }
      }

      // ---- online softmax, exp2 domain
      float tm;
      {
        const float t0 = max3f(s[0][0], s[0][1], s[0][2]);
        const float t1 = max3f(s[0][3], s[1][0], s[1][1]);
        const float t2 = max3f(s[1][2], s[1][3], s[2][0]);
        const float t3 = max3f(s[2][1], s[2][2], s[2][3]);
        const float t4 = max3f(s[3][0], s[3][1], s[3][2]);
        tm = max3f(t0, t1, s[3][3]);
        tm = max3f(tm, t2, t3);
        tm = fmaxf(tm, t4);
      }
      tm = fmaxf(tm, __shfl_xor(tm, 16));
      tm = fmaxf(tm, __shfl_xor(tm, 32));

      if (__any(tm > mrow + 8.f)) {
        const float mn = fmaxf(mrow, tm);
        const float fac = fast_exp2(mrow - mn);
        mrow = mn;
        lrow *= fac;
        float facT[4];
#pragma unroll
        for (int r = 0; r < 4; ++r)
          facT[r] = __shfl(fac, (l & 48) | (lg * 4 + r));
#pragma unroll
        for (int n = 0; n < 4; ++n)
#pragma unroll
          for (int r = 0; r < 4; ++r) acc[n][r] *= facT[r];
      }

      float rs = 0.f;
#pragma unroll
      for (int n = 0; n < 4; ++n)
#pragma unroll
        for (int r = 0; r < 4; ++r) {
          s[n][r] = fast_exp2(s[n][r] - mrow);
          rs += s[n][r];
        }
      rs += __shfl_xor(rs, 16);
      rs += __shfl_xor(rs, 32);
      lrow += rs;

      // ---- write next V tile (other buffer): overlaps the PV cluster
      if (have) {
#pragma unroll
        for (int j = 0; j < 4; ++j) {
          const unsigned int pk = (unsigned int)(unsigned short)nv0[j] |
                                  ((unsigned int)(unsigned short)nv1[j] << 16);
          *(unsigned int*)&Vt[cur ^ 1][(vd0 + j) * 64 + ((2 * vp_) ^ (((vd0 + j) & 15) * 4))] = pk;
        }
      }

      // ---- pack P in-register as PV A-frags
      v4u pu0, pu1;
      pu0.x = cvt_pk_bf16(s[0][0], s[0][1]); pu0.y = cvt_pk_bf16(s[0][2], s[0][3]);
      pu0.z = cvt_pk_bf16(s[1][0], s[1][1]); pu0.w = cvt_pk_bf16(s[1][2], s[1][3]);
      pu1.x = cvt_pk_bf16(s[2][0], s[2][1]); pu1.y = cvt_pk_bf16(s[2][2], s[2][3]);
      pu1.z = cvt_pk_bf16(s[3][0], s[3][1]); pu1.w = cvt_pk_bf16(s[3][2], s[3][3]);
      v8s pf0, pf1;
      __builtin_memcpy(&pf0, &pu0, 16);
      __builtin_memcpy(&pf1, &pu1, 16);

      // ---- PV: B-frag of V with the same k-slot map; 2x ds_read_b64 each
      __builtin_amdgcn_s_setprio(1);
#pragma unroll
      for (int kk = 0; kk < 2; ++kk) {
#pragma unroll
        for (int n = 0; n < 4; ++n) {
          const int rowb = (n * 16 + lr) * 64;
          const v4s va_ = *(const v4s*)&Vt[cur][rowb + ((kk * 32 + lg * 4) ^ vswz)];
          const v4s vb_ = *(const v4s*)&Vt[cur][rowb + ((kk * 32 + 16 + lg * 4) ^ vswz)];
          const v8s vf = __builtin_shufflevector(va_, vb_, 0, 1, 2, 3, 4, 5, 6, 7);
          acc[n] = MFMA16(kk ? pf1 : pf0, vf, acc[n]);
        }
      }
      __builtin_amdgcn_s_setprio(0);
      __syncthreads();   // drains gl_lds (vmcnt) + V writes: next tile ready
      cur ^= 1;
    }

    // ---- epilogue: O = acc / l
    float lT[4];
#pragma unroll
    for (int r = 0; r < 4; ++r)
      lT[r] = __shfl(lrow, (l & 48) | (lg * 4 + r));
#pragma unroll
    for (int n = 0; n < 4; ++n)
#pragma unroll
      for (int r = 0; r < 4; ++r) {
        const float v = acc[n][r] / lT[r];
        O[baseo + (size_t)(q0w + lg * 4 + r) * 1024 + n * 16 + lr] = f2bf(v);
      }
  }
}

// ---------------------------------------------------------------------------
// Fused (optional residual-add +) LayerNorm, bf16 in / bf16 and-or f32 out.
// ---------------------------------------------------------------------------
__global__ __launch_bounds__(256)
void add_ln(const unsigned short* __restrict__ ra, const unsigned short* __restrict__ rb,
            const float* __restrict__ g, const float* __restrict__ be,
            unsigned short* __restrict__ ob, float* __restrict__ of) {
  const int t = blockIdx.x, tid = threadIdx.x;
  const ushort4 ua = ((const ushort4*)(ra + (size_t)t * 1024))[tid];
  float4 s;
  s.x = bf2f(ua.x); s.y = bf2f(ua.y); s.z = bf2f(ua.z); s.w = bf2f(ua.w);
  if (rb) {
    const ushort4 ub = ((const ushort4*)(rb + (size_t)t * 1024))[tid];
    s.x += bf2f(ub.x); s.y += bf2f(ub.y); s.z += bf2f(ub.z); s.w += bf2f(ub.w);
  }
  float sum = s.x + s.y + s.z + s.w;
  float sq  = s.x * s.x + s.y * s.y + s.z * s.z + s.w * s.w;
#pragma unroll
  for (int off = 32; off > 0; off >>= 1) {
    sum += __shfl_xor(sum, off);
    sq  += __shfl_xor(sq, off);
  }
  __shared__ float red[8];
  const int w = tid >> 6;
  if ((tid & 63) == 0) { red[w] = sum; red[4 + w] = sq; }
  __syncthreads();
  sum = red[0] + red[1] + red[2] + red[3];
  sq  = red[4] + red[5] + red[6] + red[7];
  const float mean = sum * (1.f / 1024.f);
  const float var  = sq * (1.f / 1024.f) - mean * mean;
  const float rstd = rsqrtf(var + 1e-5f);
  const float4 gg = ((const float4*)g)[tid];
  const float4 bb = ((const float4*)be)[tid];
  float4 y;
  y.x = (s.x - mean) * rstd * gg.x + bb.x;
  y.y = (s.y - mean) * rstd * gg.y + bb.y;
  y.z = (s.z - mean) * rstd * gg.z + bb.z;
  y.w = (s.w - mean) * rstd * gg.w + bb.w;
  if (ob) {
    ushort4 u;
    u.x = f2bf(y.x); u.y = f2bf(y.y); u.z = f2bf(y.z); u.w = f2bf(y.w);
    ((ushort4*)(ob + (size_t)t * 1024))[tid] = u;
  }
  if (of) ((float4*)(of + (size_t)t * 1024))[tid] = y;
}

// ---------------------------------------------------------------------------
extern "C" void kernel_launch(void* const* d_in, const int* in_sizes, int n_in,
                              void* d_out, int out_size, void* d_ws, size_t ws_size,
                              hipStream_t stream) {
  const int*   x    = (const int*)d_in[0];
  const float* tok  = (const float*)d_in[1];
  const float* pos  = (const float*)d_in[2];
  const float* mWq  = (const float*)d_in[3];
  const float* mWk  = (const float*)d_in[4];
  const float* mWv  = (const float*)d_in[5];
  const float* mWo  = (const float*)d_in[6];
  const float* m_bo = (const float*)d_in[7];
  const float* hWq  = (const float*)d_in[8];
  const float* hWk  = (const float*)d_in[9];
  const float* hWv  = (const float*)d_in[10];
  const float* hWo  = (const float*)d_in[11];
  const float* h_bo = (const float*)d_in[12];
  const float* fW1  = (const float*)d_in[13];
  const float* f_b1 = (const float*)d_in[14];
  const float* fW2  = (const float*)d_in[15];
  const float* f_b2 = (const float*)d_in[16];
  const float* fW3  = (const float*)d_in[17];
  const float* f_b3 = (const float*)d_in[18];
  const float* fW4  = (const float*)d_in[19];
  const float* f_b4 = (const float*)d_in[20];
  const float* ln_g = (const float*)d_in[21];
  const float* ln_b = (const float*)d_in[22];

  char* ws = (char*)d_ws;
  const size_t MB = 1ull << 20;
  unsigned short* wqkv1 = (unsigned short*)(ws + 0 * MB);    // [3072][1024] 6 MB
  unsigned short* wqkv2 = (unsigned short*)(ws + 6 * MB);    // 6 MB
  unsigned short* wo1   = (unsigned short*)(ws + 12 * MB);   // 2 MB
  unsigned short* wo2   = (unsigned short*)(ws + 14 * MB);   // 2 MB
  unsigned short* fW1_t = (unsigned short*)(ws + 16 * MB);
  unsigned short* fW2_t = (unsigned short*)(ws + 17 * MB);
  unsigned short* fW3_t = (unsigned short*)(ws + 18 * MB);
  unsigned short* fW4_t = (unsigned short*)(ws + 19 * MB);
  unsigned short* actA  = (unsigned short*)(ws + 20 * MB);   // 16 MB
  unsigned short* actB  = (unsigned short*)(ws + 36 * MB);   // 16 MB
  unsigned short* tmp   = (unsigned short*)(ws + 52 * MB);   // 16 MB
  unsigned short* qkv   = (unsigned short*)(ws + 68 * MB);   // 48 MB (FFN overlay)
  unsigned short* h1    = (unsigned short*)(ws + 68 * MB);   // 8 MB
  unsigned short* h2    = (unsigned short*)(ws + 76 * MB);   // 16 MB
  unsigned short* h3    = (unsigned short*)(ws + 92 * MB);   // 8 MB
  unsigned short* attno = (unsigned short*)(ws + 116 * MB);  // 16 MB

  // ---- weight prep: one batched dispatch for all 12 transposes
  TransDesc td;
  td.src[0] = mWq; td.dst[0] = wqkv1;
  td.src[1] = mWk; td.dst[1] = wqkv1 + 1024 * 1024;
  td.src[2] = mWv; td.dst[2] = wqkv1 + 2048 * 1024;
  td.src[3] = mWo; td.dst[3] = wo1;
  td.src[4] = hWq; td.dst[4] = wqkv2;
  td.src[5] = hWk; td.dst[5] = wqkv2 + 1024 * 1024;
  td.src[6] = hWv; td.dst[6] = wqkv2 + 2048 * 1024;
  td.src[7] = hWo; td.dst[7] = wo2;
  td.src[8] = fW1; td.dst[8] = fW1_t;
  td.src[9] = fW2; td.dst[9] = fW2_t;
  td.src[10] = fW3; td.dst[10] = fW3_t;
  td.src[11] = fW4; td.dst[11] = fW4_t;
  transpose_all<<<10240, 256, 0, stream>>>(td);

  // ---- embedding
  embed_k<<<8192, 256, 0, stream>>>(x, tok, pos, actA);

  // ---- block 1: causal MHA (fused QKV; Q cols pre-scaled via flag bit2)
  gemm_bt<<<dim3(64, 24), 256, 0, stream>>>(actA, wqkv1, nullptr, nullptr, qkv,
                                            8192, 3072, 1024, 6);
  flash_attn<true><<<dim3(8, 64), 512, 0, stream>>>(qkv, attno);
  gemm_bt<<<dim3(64, 8), 256, 0, stream>>>(attno, wo1, m_bo, actA, tmp,
                                           8192, 1024, 1024, 10);
  add_ln<<<8192, 256, 0, stream>>>(tmp, nullptr, ln_g, ln_b, actB, nullptr);

  // ---- block 2: full (non-causal) MHA
  gemm_bt<<<dim3(64, 24), 256, 0, stream>>>(actB, wqkv2, nullptr, nullptr, qkv,
                                            8192, 3072, 1024, 6);
  flash_attn<false><<<dim3(16, 64), 512, 0, stream>>>(qkv, attno);
  gemm_bt<<<dim3(64, 8), 256, 0, stream>>>(attno, wo2, h_bo, actB, tmp,
                                           8192, 1024, 1024, 10);
  add_ln<<<8192, 256, 0, stream>>>(tmp, nullptr, ln_g, ln_b, actA, nullptr);

  // ---- FFN (overlays qkv region; qkv dead after block-2 O-proj)
  gemm_bt<<<dim3(64, 4), 256, 0, stream>>>(actA, fW1_t, f_b1, nullptr, h1,
                                           8192, 512, 1024, 3);
  gemm_bt<<<dim3(64, 8), 256, 0, stream>>>(h1, fW2_t, f_b2, nullptr, h2,
                                           8192, 1024, 512, 3);
  gemm_bt<<<dim3(64, 4), 256, 0, stream>>>(h2, fW3_t, f_b3, nullptr, h3,
                                           8192, 512, 1024, 3);
  gemm_bt<<<dim3(64, 8), 256, 0, stream>>>(h3, fW4_t, f_b4, actA, tmp,
                                           8192, 1024, 512, 10);
  add_ln<<<8192, 256, 0, stream>>>(tmp, nullptr, ln_g, ln_b, nullptr, (float*)d_out);
}

// Round 14
// 485.366 us; speedup vs baseline: 1.1632x; 1.1632x over previous
//
#include <hip/hip_runtime.h>
#include <hip/hip_bf16.h>

// ---------------------------------------------------------------------------
// Decoder block for B=4, T=2048, E=1024, H=16, HD=64, V=32000.
// bf16 MFMA compute; post-LN model -> activations/residuals stored bf16.
// R14: revert R13 (wave rebalance + epilogue fusion both regressed) to the
//      R12 structure: flash specialized waves (4-7 K gl_lds dbuf, 0-3 V-pack
//      v8s issue-early/write-late), unfused add_ln. ONE new variable: XCD-
//      chunked block swizzle on the flash grid (bijective, nwg%8==0) so all
//      blocks sharing a KV panel land on one XCD's L2.
// ---------------------------------------------------------------------------

typedef __attribute__((ext_vector_type(8))) short v8s;    // 8 bf16 (4 VGPR)
typedef __attribute__((ext_vector_type(4))) short v4s;    // 4 bf16 (b64)
typedef __attribute__((ext_vector_type(4))) float v4f;    // 16x16 accumulator
typedef __attribute__((ext_vector_type(16))) float v16f;  // 32x32 accumulator
typedef __attribute__((ext_vector_type(4))) unsigned int v4u;

#define MFMA16(a, b, c) __builtin_amdgcn_mfma_f32_16x16x32_bf16((a), (b), (c), 0, 0, 0)
#define MFMA32(a, b, c) __builtin_amdgcn_mfma_f32_32x32x16_bf16((a), (b), (c), 0, 0, 0)

typedef const __attribute__((address_space(1))) void* gas1_t;
typedef __attribute__((address_space(3))) void* las3_t;

__device__ __forceinline__ void gl_lds16(const void* g, void* l) {
  __builtin_amdgcn_global_load_lds((gas1_t)g, (las3_t)l, 16, 0, 0);
}

__device__ __forceinline__ unsigned short f2bf(float f) {
  __hip_bfloat16 h = __float2bfloat16(f);
  return *reinterpret_cast<unsigned short*>(&h);
}

__device__ __forceinline__ float bf2f(unsigned short u) {
  union { unsigned int i; float f; } v;
  v.i = (unsigned int)u << 16;
  return v.f;
}

__device__ __forceinline__ float fast_exp2(float x) {
  float r;
  asm("v_exp_f32 %0, %1" : "=v"(r) : "v"(x));
  return r;
}

__device__ __forceinline__ unsigned int cvt_pk_bf16(float lo, float hi) {
  unsigned int r;
  asm("v_cvt_pk_bf16_f32 %0, %1, %2" : "=v"(r) : "v"(lo), "v"(hi));
  return r;
}

__device__ __forceinline__ float max3f(float a, float b, float c) {
  float r;
  asm("v_max3_f32 %0, %1, %2, %3" : "=v"(r) : "v"(a), "v"(b), "v"(c));
  return r;
}

// log2(e)/sqrt(HD) folded into the Q projection
#define QSCALE 0.18033688011112042f

// ---------------------------------------------------------------------------
// Batched weight prep: 12 matrices, src[K][N] f32 -> dst[N][K] bf16.
// ---------------------------------------------------------------------------
struct TransDesc {
  const float* src[12];
  unsigned short* dst[12];
};

__global__ __launch_bounds__(256)
void transpose_all(TransDesc td) {
  const int bid = blockIdx.x;
  int m, tile, K, N;
  if (bid < 8192) { m = bid >> 10; tile = bid & 1023; K = 1024; N = 1024; }
  else {
    const int r = bid - 8192;
    m = 8 + (r >> 9); tile = r & 511;
    if (m & 1) { K = 512; N = 1024; } else { K = 1024; N = 512; }
  }
  const float* src = td.src[m];
  unsigned short* dst = td.dst[m];
  const int ntx = N >> 5;
  const int n0 = (tile % ntx) * 32, k0 = (tile / ntx) * 32;

  __shared__ float tile_s[32][33];
  const int tx = threadIdx.x & 31, ty = threadIdx.x >> 5;  // 32 x 8
#pragma unroll
  for (int i = 0; i < 32; i += 8)
    tile_s[ty + i][tx] = src[(size_t)(k0 + ty + i) * N + n0 + tx];
  __syncthreads();
#pragma unroll
  for (int i = 0; i < 32; i += 8)
    dst[(size_t)(n0 + ty + i) * K + k0 + tx] = f2bf(tile_s[tx][ty + i]);
}

// ---------------------------------------------------------------------------
// Embedding: act = bf16(tok_emb[x] + pos_emb)
// ---------------------------------------------------------------------------
__global__ __launch_bounds__(256)
void embed_k(const int* __restrict__ x, const float* __restrict__ tok,
             const float* __restrict__ pos, unsigned short* __restrict__ act) {
  const int t = blockIdx.x, tid = threadIdx.x;
  const int id = x[t], tp = t & 2047;
  float4 v = ((const float4*)(tok + (size_t)id * 1024))[tid];
  float4 p = ((const float4*)(pos + (size_t)tp * 1024))[tid];
  ushort4 u;
  u.x = f2bf(v.x + p.x); u.y = f2bf(v.y + p.y);
  u.z = f2bf(v.z + p.z); u.w = f2bf(v.w + p.w);
  ((ushort4*)(act + (size_t)t * 1024))[tid] = u;
}

// ---------------------------------------------------------------------------
// GEMM: C[M][N] = A[M][K](bf16) @ Bt[N][K]^T(bf16)  (+bias) (+relu)
// flags: bit0 relu, bit1 bf16 out, bit2 QSCALE on col<1024.
// 128x128 tile, BK=64, 4 waves (2x2), 2x2 32x32x16 MFMA per wave.
// Swizzled LDS (pre-swizzled staging + (row&7)*8 fragment XOR, conflict-free).
// C/D layout (m74/m101): col=lane&31, row=(reg&3)+8*(reg>>2)+4*(lane>>5).
// ---------------------------------------------------------------------------
__global__ __launch_bounds__(256)
void gemm_bt(const unsigned short* __restrict__ A, const unsigned short* __restrict__ Bt,
             const float* __restrict__ bias, void* __restrict__ C,
             int M, int N, int K, int flags) {
  __shared__ __align__(16) unsigned short As[128 * 64];
  __shared__ __align__(16) unsigned short Bs[128 * 64];
  const int tid = threadIdx.x;
  const int w = tid >> 6, l = tid & 63;
  const int l31 = l & 31, l5 = l >> 5;
  const int wm = w & 1, wn = w >> 1;
  const int m0 = blockIdx.x * 128, n0 = blockIdx.y * 128;
  const int ra = l >> 3, ka = ((l & 7) ^ (l >> 3)) * 8;  // pre-swizzled staging
  const int fswz = (l31 & 7) * 8;                         // fragment-read XOR

  v16f acc[2][2];
#pragma unroll
  for (int bm = 0; bm < 2; ++bm)
#pragma unroll
    for (int bn = 0; bn < 2; ++bn)
#pragma unroll
      for (int r = 0; r < 16; ++r) acc[bm][bn][r] = 0.f;

  for (int k0 = 0; k0 < K; k0 += 64) {
#pragma unroll
    for (int i = 0; i < 4; ++i) {
      const int c = w + i * 4;
      gl_lds16(A  + (size_t)(m0 + c * 8 + ra) * K + k0 + ka, &As[c * 512]);
      gl_lds16(Bt + (size_t)(n0 + c * 8 + ra) * K + k0 + ka, &Bs[c * 512]);
    }
    __syncthreads();
#pragma unroll
    for (int kk = 0; kk < 4; ++kk) {
      const int co = (kk * 16 + l5 * 8) ^ fswz;
      const v8s a0 = *(const v8s*)&As[(wm * 64 + l31) * 64 + co];
      const v8s a1 = *(const v8s*)&As[(wm * 64 + 32 + l31) * 64 + co];
      const v8s b0 = *(const v8s*)&Bs[(wn * 64 + l31) * 64 + co];
      const v8s b1 = *(const v8s*)&Bs[(wn * 64 + 32 + l31) * 64 + co];
      acc[0][0] = MFMA32(a0, b0, acc[0][0]);
      acc[0][1] = MFMA32(a0, b1, acc[0][1]);
      acc[1][0] = MFMA32(a1, b0, acc[1][0]);
      acc[1][1] = MFMA32(a1, b1, acc[1][1]);
    }
    __syncthreads();
  }

  const bool relu = flags & 1, obf = flags & 2, qs = flags & 4;
#pragma unroll
  for (int bn = 0; bn < 2; ++bn) {
    const int col = n0 + wn * 64 + bn * 32 + l31;
    const float bv = bias ? bias[col] : 0.f;
    const float sc = (qs && col < 1024) ? QSCALE : 1.f;
#pragma unroll
    for (int bm = 0; bm < 2; ++bm) {
      const int rowbase = m0 + wm * 64 + bm * 32 + 4 * l5;
#pragma unroll
      for (int r = 0; r < 16; ++r) {
        const int row = rowbase + (r & 3) + 8 * (r >> 2);
        float v = (acc[bm][bn][r] + bv) * sc;
        if (relu) v = fmaxf(v, 0.f);
        if (obf) ((unsigned short*)C)[(size_t)row * N + col] = f2bf(v);
        else     ((float*)C)[(size_t)row * N + col] = v;
      }
    }
  }
}

// ---------------------------------------------------------------------------
// Flash attention over fused QKV buffer [8192][3072] bf16 (Q cols h*64..,
// K cols 1024+h*64.., V cols 2048+h*64..). 512 threads = 8 waves, 128 q
// rows/block. Single-barrier double-buffered K/V with SPECIALIZED waves
// (R12 structure, measured best): waves 4-7 issue K(t+1) gl_lds into
// Kt[cur^1]; waves 0-3 issue V(t+1) global->reg (v8s) early and pack into
// Vt[cur^1] after softmax. ONE __syncthreads per tile.
// Swapped QK^T, in-reg softmax; Kt swz (kv&7)*8, Vt swz (d&15)*4
// (measured conflict-free R7-R12).
// NEW (R14): XCD-chunked block swizzle — consecutive linear blocks share a
// KV panel; chunking puts each panel's blocks on one XCD's L2.
// CAUSAL: 16 q-tiles of 128, block handles pair (bx, 15-bx).
// ---------------------------------------------------------------------------
#define LDQ 3072
template <bool CAUSAL>
__global__ __launch_bounds__(512)
void flash_attn(const unsigned short* __restrict__ qkv, unsigned short* __restrict__ O) {
  __shared__ __align__(16) unsigned short Kt[2][64 * 64];   // [kv][d], swizzled
  __shared__ __align__(16) unsigned short Vt[2][64 * 64];   // [d][kv], swizzled
  const int tid = threadIdx.x;
  const int w = tid >> 6, l = tid & 63, lr = l & 15, lg = l >> 4;
  // XCD-chunked swizzle (bijective: nwg % 8 == 0 for both grids)
  const int gx = (int)gridDim.x;
  const int lin = (int)blockIdx.x + gx * (int)blockIdx.y;
  const int cpx = (gx * (int)gridDim.y) >> 3;
  const int nl = (lin & 7) * cpx + (lin >> 3);
  const int bx = nl % gx, by = nl / gx;
  const int b = by >> 4, h = by & 15;
  const size_t baseq = ((size_t)b * 2048) * LDQ + h * 64;   // QKV slice base
  const size_t baseo = ((size_t)b * 2048) * 1024 + h * 64;  // O slice base
  const int kswz = (lr & 7) * 8;    // K fragment-read XOR (elems)
  const int vswz = lr * 4;          // V fragment-read XOR: sigma(d)=(d&15)*4

  const int kra = l >> 3, kka = ((l & 7) ^ (l >> 3)) * 8;
  const int vp_ = tid & 31, vd0 = ((tid >> 5) & 7) * 8;
  const unsigned short* Kbase = qkv + baseq + 1024 + (size_t)kra * LDQ + kka;
  const unsigned short* Vbase = qkv + baseq + 2048 + (size_t)(2 * vp_) * LDQ + vd0;

  const int nq = CAUSAL ? 2 : 1;
  for (int qi = 0; qi < nq; ++qi) {
    const int qt = CAUSAL ? (qi ? 15 - bx : bx) : bx;
    const int q0w = qt * 128 + w * 16;                      // this wave's q base

    const unsigned short* qp = qkv + baseq + (size_t)(q0w + lr) * LDQ + lg * 8;
    const v8s qf0 = *(const v8s*)qp;
    const v8s qf1 = *(const v8s*)(qp + 32);

    v4f acc[4];
    const v4f vzero = {0.f, 0.f, 0.f, 0.f};
#pragma unroll
    for (int n = 0; n < 4; ++n) acc[n] = vzero;
    float mrow = -INFINITY, lrow = 0.f;                     // state for q = lr

    const int kv_end = CAUSAL ? qt * 128 + 128 : 2048;

    // ---- prologue: stage tile 0 into buffer 0
    if (w >= 4) {
#pragma unroll
      for (int i = 0; i < 2; ++i) {
        const int c = (w - 4) * 2 + i;
        gl_lds16(Kbase + (size_t)(c * 8) * LDQ, &Kt[0][c * 512]);
      }
    } else {
      const v8s v0 = *(const v8s*)Vbase;
      const v8s v1 = *(const v8s*)(Vbase + LDQ);
#pragma unroll
      for (int j = 0; j < 8; ++j) {
        const unsigned int pk = (unsigned int)(unsigned short)v0[j] |
                                ((unsigned int)(unsigned short)v1[j] << 16);
        *(unsigned int*)&Vt[0][(vd0 + j) * 64 + ((2 * vp_) ^ (((vd0 + j) & 15) * 4))] = pk;
      }
    }
    __syncthreads();

    int cur = 0;
    for (int kv0 = 0; kv0 < kv_end; kv0 += 64) {
      const bool have = (kv0 + 64) < kv_end;
      // ---- issue next-tile loads early (K async->LDS by waves 4-7;
      //      V global->reg by waves 0-3)
      v8s nv0, nv1;
      if (w >= 4) {
        if (have) {
          const int nxt = kv0 + 64;
#pragma unroll
          for (int i = 0; i < 2; ++i) {
            const int c = (w - 4) * 2 + i;
            gl_lds16(Kbase + (size_t)(nxt + c * 8) * LDQ, &Kt[cur ^ 1][c * 512]);
          }
        }
      } else if (have) {
        const unsigned short* va = Vbase + (size_t)(kv0 + 64) * LDQ;
        nv0 = *(const v8s*)va;
        nv1 = *(const v8s*)(va + LDQ);
      }

      // ---- S^T = mfma(K, Q): s[n][r] = S[kv = kv0+n*16+lg*4+r][q = q0w+lr]
      v4f s[4];
#pragma unroll
      for (int n = 0; n < 4; ++n) s[n] = vzero;
      __builtin_amdgcn_s_setprio(1);
#pragma unroll
      for (int kk = 0; kk < 2; ++kk) {
#pragma unroll
        for (int n = 0; n < 4; ++n) {
          const v8s kf = *(const v8s*)&Kt[cur][(n * 16 + lr) * 64 + ((kk * 32 + lg * 8) ^ kswz)];
          s[n] = MFMA16(kf, kk ? qf1 : qf0, s[n]);
        }
      }
      __builtin_amdgcn_s_setprio(0);

      if (CAUSAL && (kv0 + 63 > q0w)) {
        const int qg = q0w + lr;
#pragma unroll
        for (int n = 0; n < 4; ++n) {
          const int kvb = kv0 + n * 16 + lg * 4;
#pragma unroll
          for (int r = 0; r < 4; ++r)
            if (kvb + r > qg) s[n][r] = -INFINITY;
        }
      }

      // ---- online softmax, exp2 domain
      float tm;
      {
        const float t0 = max3f(s[0][0], s[0][1], s[0][2]);
        const float t1 = max3f(s[0][3], s[1][0], s[1][1]);
        const float t2 = max3f(s[1][2], s[1][3], s[2][0]);
        const float t3 = max3f(s[2][1], s[2][2], s[2][3]);
        const float t4 = max3f(s[3][0], s[3][1], s[3][2]);
        tm = max3f(t0, t1, s[3][3]);
        tm = max3f(tm, t2, t3);
        tm = fmaxf(tm, t4);
      }
      tm = fmaxf(tm, __shfl_xor(tm, 16));
      tm = fmaxf(tm, __shfl_xor(tm, 32));

      if (__any(tm > mrow + 8.f)) {
        const float mn = fmaxf(mrow, tm);
        const float fac = fast_exp2(mrow - mn);
        mrow = mn;
        lrow *= fac;
        float facT[4];
#pragma unroll
        for (int r = 0; r < 4; ++r)
          facT[r] = __shfl(fac, (l & 48) | (lg * 4 + r));
#pragma unroll
        for (int n = 0; n < 4; ++n)
#pragma unroll
          for (int r = 0; r < 4; ++r) acc[n][r] *= facT[r];
      }

      float rs = 0.f;
#pragma unroll
      for (int n = 0; n < 4; ++n)
#pragma unroll
        for (int r = 0; r < 4; ++r) {
          s[n][r] = fast_exp2(s[n][r] - mrow);
          rs += s[n][r];
        }
      rs += __shfl_xor(rs, 16);
      rs += __shfl_xor(rs, 32);
      lrow += rs;

      // ---- write next V tile (other buffer): load latency hidden under
      //      QK^T+softmax, writes overlap the PV cluster
      if (w < 4 && have) {
#pragma unroll
        for (int j = 0; j < 8; ++j) {
          const unsigned int pk = (unsigned int)(unsigned short)nv0[j] |
                                  ((unsigned int)(unsigned short)nv1[j] << 16);
          *(unsigned int*)&Vt[cur ^ 1][(vd0 + j) * 64 + ((2 * vp_) ^ (((vd0 + j) & 15) * 4))] = pk;
        }
      }

      // ---- pack P in-register as PV A-frags
      v4u pu0, pu1;
      pu0.x = cvt_pk_bf16(s[0][0], s[0][1]); pu0.y = cvt_pk_bf16(s[0][2], s[0][3]);
      pu0.z = cvt_pk_bf16(s[1][0], s[1][1]); pu0.w = cvt_pk_bf16(s[1][2], s[1][3]);
      pu1.x = cvt_pk_bf16(s[2][0], s[2][1]); pu1.y = cvt_pk_bf16(s[2][2], s[2][3]);
      pu1.z = cvt_pk_bf16(s[3][0], s[3][1]); pu1.w = cvt_pk_bf16(s[3][2], s[3][3]);
      v8s pf0, pf1;
      __builtin_memcpy(&pf0, &pu0, 16);
      __builtin_memcpy(&pf1, &pu1, 16);

      // ---- PV: B-frag of V with the same k-slot map; 2x ds_read_b64 each
      __builtin_amdgcn_s_setprio(1);
#pragma unroll
      for (int kk = 0; kk < 2; ++kk) {
#pragma unroll
        for (int n = 0; n < 4; ++n) {
          const int rowb = (n * 16 + lr) * 64;
          const v4s va_ = *(const v4s*)&Vt[cur][rowb + ((kk * 32 + lg * 4) ^ vswz)];
          const v4s vb_ = *(const v4s*)&Vt[cur][rowb + ((kk * 32 + 16 + lg * 4) ^ vswz)];
          const v8s vf = __builtin_shufflevector(va_, vb_, 0, 1, 2, 3, 4, 5, 6, 7);
          acc[n] = MFMA16(kk ? pf1 : pf0, vf, acc[n]);
        }
      }
      __builtin_amdgcn_s_setprio(0);
      __syncthreads();   // drains gl_lds (vmcnt) + V writes: next tile ready
      cur ^= 1;
    }

    // ---- epilogue: O = acc / l
    float lT[4];
#pragma unroll
    for (int r = 0; r < 4; ++r)
      lT[r] = __shfl(lrow, (l & 48) | (lg * 4 + r));
#pragma unroll
    for (int n = 0; n < 4; ++n)
#pragma unroll
      for (int r = 0; r < 4; ++r) {
        const float v = acc[n][r] / lT[r];
        O[baseo + (size_t)(q0w + lg * 4 + r) * 1024 + n * 16 + lr] = f2bf(v);
      }
  }
}

// ---------------------------------------------------------------------------
// Fused residual-add + LayerNorm, bf16 in / bf16 and-or f32 out.
// ---------------------------------------------------------------------------
__global__ __launch_bounds__(256)
void add_ln(const unsigned short* __restrict__ ra, const unsigned short* __restrict__ rb,
            const float* __restrict__ g, const float* __restrict__ be,
            unsigned short* __restrict__ ob, float* __restrict__ of) {
  const int t = blockIdx.x, tid = threadIdx.x;
  const ushort4 ua = ((const ushort4*)(ra + (size_t)t * 1024))[tid];
  const ushort4 ub = ((const ushort4*)(rb + (size_t)t * 1024))[tid];
  float4 s;
  s.x = bf2f(ua.x) + bf2f(ub.x);
  s.y = bf2f(ua.y) + bf2f(ub.y);
  s.z = bf2f(ua.z) + bf2f(ub.z);
  s.w = bf2f(ua.w) + bf2f(ub.w);
  float sum = s.x + s.y + s.z + s.w;
  float sq  = s.x * s.x + s.y * s.y + s.z * s.z + s.w * s.w;
#pragma unroll
  for (int off = 32; off > 0; off >>= 1) {
    sum += __shfl_xor(sum, off);
    sq  += __shfl_xor(sq, off);
  }
  __shared__ float red[8];
  const int w = tid >> 6;
  if ((tid & 63) == 0) { red[w] = sum; red[4 + w] = sq; }
  __syncthreads();
  sum = red[0] + red[1] + red[2] + red[3];
  sq  = red[4] + red[5] + red[6] + red[7];
  const float mean = sum * (1.f / 1024.f);
  const float var  = sq * (1.f / 1024.f) - mean * mean;
  const float rstd = rsqrtf(var + 1e-5f);
  const float4 gg = ((const float4*)g)[tid];
  const float4 bb = ((const float4*)be)[tid];
  float4 y;
  y.x = (s.x - mean) * rstd * gg.x + bb.x;
  y.y = (s.y - mean) * rstd * gg.y + bb.y;
  y.z = (s.z - mean) * rstd * gg.z + bb.z;
  y.w = (s.w - mean) * rstd * gg.w + bb.w;
  if (ob) {
    ushort4 u;
    u.x = f2bf(y.x); u.y = f2bf(y.y); u.z = f2bf(y.z); u.w = f2bf(y.w);
    ((ushort4*)(ob + (size_t)t * 1024))[tid] = u;
  }
  if (of) ((float4*)(of + (size_t)t * 1024))[tid] = y;
}

// ---------------------------------------------------------------------------
extern "C" void kernel_launch(void* const* d_in, const int* in_sizes, int n_in,
                              void* d_out, int out_size, void* d_ws, size_t ws_size,
                              hipStream_t stream) {
  const int*   x    = (const int*)d_in[0];
  const float* tok  = (const float*)d_in[1];
  const float* pos  = (const float*)d_in[2];
  const float* mWq  = (const float*)d_in[3];
  const float* mWk  = (const float*)d_in[4];
  const float* mWv  = (const float*)d_in[5];
  const float* mWo  = (const float*)d_in[6];
  const float* m_bo = (const float*)d_in[7];
  const float* hWq  = (const float*)d_in[8];
  const float* hWk  = (const float*)d_in[9];
  const float* hWv  = (const float*)d_in[10];
  const float* hWo  = (const float*)d_in[11];
  const float* h_bo = (const float*)d_in[12];
  const float* fW1  = (const float*)d_in[13];
  const float* f_b1 = (const float*)d_in[14];
  const float* fW2  = (const float*)d_in[15];
  const float* f_b2 = (const float*)d_in[16];
  const float* fW3  = (const float*)d_in[17];
  const float* f_b3 = (const float*)d_in[18];
  const float* fW4  = (const float*)d_in[19];
  const float* f_b4 = (const float*)d_in[20];
  const float* ln_g = (const float*)d_in[21];
  const float* ln_b = (const float*)d_in[22];

  char* ws = (char*)d_ws;
  const size_t MB = 1ull << 20;
  unsigned short* wqkv1 = (unsigned short*)(ws + 0 * MB);    // [3072][1024] 6 MB
  unsigned short* wqkv2 = (unsigned short*)(ws + 6 * MB);    // 6 MB
  unsigned short* wo1   = (unsigned short*)(ws + 12 * MB);   // 2 MB
  unsigned short* wo2   = (unsigned short*)(ws + 14 * MB);   // 2 MB
  unsigned short* fW1_t = (unsigned short*)(ws + 16 * MB);
  unsigned short* fW2_t = (unsigned short*)(ws + 17 * MB);
  unsigned short* fW3_t = (unsigned short*)(ws + 18 * MB);
  unsigned short* fW4_t = (unsigned short*)(ws + 19 * MB);
  unsigned short* actA  = (unsigned short*)(ws + 20 * MB);   // 16 MB
  unsigned short* actB  = (unsigned short*)(ws + 36 * MB);   // 16 MB
  unsigned short* tmp   = (unsigned short*)(ws + 52 * MB);   // 16 MB
  unsigned short* qkv   = (unsigned short*)(ws + 68 * MB);   // 48 MB (FFN overlay)
  unsigned short* h1    = (unsigned short*)(ws + 68 * MB);   // 8 MB
  unsigned short* h2    = (unsigned short*)(ws + 76 * MB);   // 16 MB
  unsigned short* h3    = (unsigned short*)(ws + 92 * MB);   // 8 MB
  unsigned short* attno = (unsigned short*)(ws + 116 * MB);  // 16 MB

  // ---- weight prep: one batched dispatch for all 12 transposes
  TransDesc td;
  td.src[0] = mWq; td.dst[0] = wqkv1;
  td.src[1] = mWk; td.dst[1] = wqkv1 + 1024 * 1024;
  td.src[2] = mWv; td.dst[2] = wqkv1 + 2048 * 1024;
  td.src[3] = mWo; td.dst[3] = wo1;
  td.src[4] = hWq; td.dst[4] = wqkv2;
  td.src[5] = hWk; td.dst[5] = wqkv2 + 1024 * 1024;
  td.src[6] = hWv; td.dst[6] = wqkv2 + 2048 * 1024;
  td.src[7] = hWo; td.dst[7] = wo2;
  td.src[8] = fW1; td.dst[8] = fW1_t;
  td.src[9] = fW2; td.dst[9] = fW2_t;
  td.src[10] = fW3; td.dst[10] = fW3_t;
  td.src[11] = fW4; td.dst[11] = fW4_t;
  transpose_all<<<10240, 256, 0, stream>>>(td);

  // ---- embedding
  embed_k<<<8192, 256, 0, stream>>>(x, tok, pos, actA);

  // ---- block 1: causal MHA (fused QKV; Q cols pre-scaled via flag bit2)
  gemm_bt<<<dim3(64, 24), 256, 0, stream>>>(actA, wqkv1, nullptr, qkv, 8192, 3072, 1024, 6);
  flash_attn<true><<<dim3(8, 64), 512, 0, stream>>>(qkv, attno);
  gemm_bt<<<dim3(64, 8), 256, 0, stream>>>(attno, wo1, m_bo, tmp, 8192, 1024, 1024, 2);
  add_ln<<<8192, 256, 0, stream>>>(actA, tmp, ln_g, ln_b, actB, nullptr);

  // ---- block 2: full (non-causal) MHA
  gemm_bt<<<dim3(64, 24), 256, 0, stream>>>(actB, wqkv2, nullptr, qkv, 8192, 3072, 1024, 6);
  flash_attn<false><<<dim3(16, 64), 512, 0, stream>>>(qkv, attno);
  gemm_bt<<<dim3(64, 8), 256, 0, stream>>>(attno, wo2, h_bo, tmp, 8192, 1024, 1024, 2);
  add_ln<<<8192, 256, 0, stream>>>(actB, tmp, ln_g, ln_b, actA, nullptr);

  // ---- FFN (overlays qkv region; qkv dead after block-2 O-proj)
  gemm_bt<<<dim3(64, 4), 256, 0, stream>>>(actA, fW1_t, f_b1, h1, 8192, 512, 1024, 3);
  gemm_bt<<<dim3(64, 8), 256, 0, stream>>>(h1, fW2_t, f_b2, h2, 8192, 1024, 512, 3);
  gemm_bt<<<dim3(64, 4), 256, 0, stream>>>(h2, fW3_t, f_b3, h3, 8192, 512, 1024, 3);
  gemm_bt<<<dim3(64, 8), 256, 0, stream>>>(h3, fW4_t, f_b4, tmp, 8192, 1024, 512, 2);
  add_ln<<<8192, 256, 0, stream>>>(actA, tmp, ln_g, ln_b, nullptr, (float*)d_out);
}